// Round 7
// baseline (158.280 us; speedup 1.0000x reference)
//
#include <hip/hip_runtime.h>
#include <hip/hip_bf16.h>

// Problem constants: B=8, S=2048, E=768, HEAD=128
#define BB 8
#define SS 2048
#define EE 768
#define HH 128
#define MM (BB*SS)     // 16384
#define NQT 32         // 64-row q-tiles per batch
#define NCH 144        // chunks per batch: sum_{qt} ceil((qt+1)/4)

typedef __attribute__((ext_vector_type(8))) short bf16x8;
typedef __attribute__((ext_vector_type(8))) unsigned short ushort8;
typedef __attribute__((ext_vector_type(4))) float f32x4;

__device__ __forceinline__ unsigned short f2bf(float x) {
    unsigned int u = __float_as_uint(x);
    u += 0x7fff + ((u >> 16) & 1);   // RNE
    return (unsigned short)(u >> 16);
}
__device__ __forceinline__ float bf2f(unsigned short h) {
    return __uint_as_float(((unsigned int)h) << 16);
}
// async global->LDS, 16B per lane; LDS dest = wave-uniform base + lane*16
__device__ __forceinline__ void gld16(const unsigned short* g, unsigned short* l) {
    __builtin_amdgcn_global_load_lds(
        (const __attribute__((address_space(1))) unsigned int*)g,
        (__attribute__((address_space(3))) unsigned int*)l, 16, 0, 0);
}

// ---------------------------------------------------------------------------
// wcvt: Wb = bf16([Wq;Wk;Wv]) [384][768]. grid 288, ~2 us.
// ---------------------------------------------------------------------------
__global__ __launch_bounds__(256)
void wcvt(const float* __restrict__ Wq, const float* __restrict__ Wk,
          const float* __restrict__ Wv, unsigned short* __restrict__ Wb) {
    int i4 = (blockIdx.x * 256 + threadIdx.x) * 4;        // < 294912
    const float* src; int off;
    if (i4 < 98304)       { src = Wq; off = i4; }
    else if (i4 < 196608) { src = Wk; off = i4 - 98304; }
    else                  { src = Wv; off = i4 - 196608; }
    float4 v = *(const float4*)(src + off);
    ushort4 o;
    o.x = f2bf(v.x); o.y = f2bf(v.y); o.z = f2bf(v.z); o.w = f2bf(v.w);
    *(ushort4*)(Wb + i4) = o;
}

// ---------------------------------------------------------------------------
// Fused QKV GEMM: X read ONCE. m-tile 64, N=384 (Q|K|V), BK=32, 24 k-iters,
// double-buffered LDS (2 x (A 4KB + B 24KB) = 56KB). grid 256 (1 block/CU),
// 4 waves: wave w owns cols [w*96, w*96+96) (6 col-tiles), all 64 rows.
// A: X fp32 -> masked bf16 in-register -> ds_write_b128. B: gld16 from Wb.
// Swizzle slot = chunk ^ ((row>>1)&3): 2-way (free) on all b128 ops.
// Pipeline per iter: barrier -> issue next B gld16 + next A float4 loads ->
// 24 MFMA on current -> convert/ds_write next A (vmcnt wait lands AFTER MFMA).
// ---------------------------------------------------------------------------
__global__ __launch_bounds__(256, 1)
void qkv_fused(const float* __restrict__ X, const float* __restrict__ mask,
               const unsigned short* __restrict__ Wb,
               unsigned short* __restrict__ Q, unsigned short* __restrict__ K,
               unsigned short* __restrict__ Vt)
{
    const int m0 = blockIdx.x * 64;

    // per-buf: A 2048 shorts | B 12288 shorts; two bufs = 28672 shorts (56KB)
    __shared__ __align__(16) unsigned short SM[28672];

    const int t = threadIdx.x, lane = t & 63;
    const int quad = lane >> 4, l16 = lane & 15;
    const int wave = t >> 6;
    const int wub = (t & 192) * 8;           // wave-uniform chunk base (shorts)

    // A-staging assignment: thread -> (row, 8-col segment)
    const int arow = t >> 2, aseg = t & 3;
    const int ap = aseg ^ ((arow >> 1) & 3); // swizzled physical slot
    const float* xrow = X + (size_t)(m0 + arow) * EE;
    const float amk = mask[m0 + arow];

    f32x4 acc[4][6];
#pragma unroll
    for (int i = 0; i < 4; i++)
#pragma unroll
        for (int ct = 0; ct < 6; ct++) acc[i][ct] = (f32x4)0.0f;

    // ---- prologue: stage k-slice 0 into buf 0 ----
    {
        unsigned short* Bd = SM + 2048;
#pragma unroll
        for (int i = 0; i < 6; i++) {
            int cg = i * 256 + t;
            int row = cg >> 2;
            int cc = (cg & 3) ^ ((row >> 1) & 3);
            gld16(Wb + (size_t)row * EE + cc * 8, Bd + i * 2048 + wub);
        }
        float4 xa = *(const float4*)(xrow + aseg * 8);
        float4 xb = *(const float4*)(xrow + aseg * 8 + 4);
        ushort8 u;
        u[0] = f2bf(xa.x * amk); u[1] = f2bf(xa.y * amk);
        u[2] = f2bf(xa.z * amk); u[3] = f2bf(xa.w * amk);
        u[4] = f2bf(xb.x * amk); u[5] = f2bf(xb.y * amk);
        u[6] = f2bf(xb.z * amk); u[7] = f2bf(xb.w * amk);
        *(ushort8*)&SM[arow * 32 + ap * 8] = u;
    }

    for (int kt = 0; kt < 24; kt++) {
        const int cur = kt & 1, nxt = cur ^ 1;
        __syncthreads();   // staging of `cur` (gld16 vmcnt + ds_writes) complete

        float4 xa, xb;
        const bool more = (kt + 1 < 24);
        if (more) {
            const int kn = (kt + 1) * 32;
            unsigned short* Bd = SM + nxt * 14336 + 2048;
#pragma unroll
            for (int i = 0; i < 6; i++) {
                int cg = i * 256 + t;
                int row = cg >> 2;
                int cc = (cg & 3) ^ ((row >> 1) & 3);
                gld16(Wb + (size_t)row * EE + kn + cc * 8, Bd + i * 2048 + wub);
            }
            xa = *(const float4*)(xrow + kn + aseg * 8);
            xb = *(const float4*)(xrow + kn + aseg * 8 + 4);
        }

        // compute on current buffer
        {
            const unsigned short* Ab = SM + cur * 14336;
            const unsigned short* Bb = Ab + 2048;
            bf16x8 a[4], bfr[6];
#pragma unroll
            for (int i = 0; i < 4; i++) {
                int row = i * 16 + l16;
                a[i] = *(const bf16x8*)&Ab[row * 32 + ((quad ^ ((row >> 1) & 3)) << 3)];
            }
#pragma unroll
            for (int ct = 0; ct < 6; ct++) {
                int row = wave * 96 + ct * 16 + l16;
                bfr[ct] = *(const bf16x8*)&Bb[row * 32 + ((quad ^ ((row >> 1) & 3)) << 3)];
            }
#pragma unroll
            for (int i = 0; i < 4; i++)
#pragma unroll
                for (int ct = 0; ct < 6; ct++)
                    acc[i][ct] = __builtin_amdgcn_mfma_f32_16x16x32_bf16(a[i], bfr[ct], acc[i][ct], 0, 0, 0);
        }

        if (more) {   // convert + ds_write next A (X-load vmcnt wait lands here)
            ushort8 u;
            u[0] = f2bf(xa.x * amk); u[1] = f2bf(xa.y * amk);
            u[2] = f2bf(xa.z * amk); u[3] = f2bf(xa.w * amk);
            u[4] = f2bf(xb.x * amk); u[5] = f2bf(xb.y * amk);
            u[6] = f2bf(xb.z * amk); u[7] = f2bf(xb.w * amk);
            *(ushort8*)&SM[nxt * 14336 + arow * 32 + ap * 8] = u;
        }
    }

    // ---- epilogue: route n -> Q / K (direct) and V (LDS-bounce transpose) ----
    // C/D layout: row = quad*4 + r, col = l16  [measured: m89/m91]
#pragma unroll
    for (int i = 0; i < 4; i++)
#pragma unroll
        for (int r = 0; r < 4; r++) {
            int m = m0 + i * 16 + quad * 4 + r;
#pragma unroll
            for (int ct = 0; ct < 6; ct++) {
                int n = wave * 96 + ct * 16 + l16;
                if (n < 128)      Q[(size_t)m * HH + n] = f2bf(acc[i][ct][r]);
                else if (n < 256) K[(size_t)m * HH + (n - 128)] = f2bf(acc[i][ct][r]);
            }
        }
    // V: waves 2,3 hold cols >=256. Bounce through SM[0..8192): [h][tok].
    // (safe: after iter-23 barrier no wave reads buf0; compute(23) reads buf1)
#pragma unroll
    for (int i = 0; i < 4; i++)
#pragma unroll
        for (int r = 0; r < 4; r++) {
            int tok = i * 16 + quad * 4 + r;
            int cc = tok >> 3, wd = tok & 7;
#pragma unroll
            for (int ct = 0; ct < 6; ct++) {
                int n = wave * 96 + ct * 16 + l16;
                if (n >= 256) {
                    int h = n - 256;
                    SM[h * 64 + ((cc ^ (h & 7)) << 3) + wd] = f2bf(acc[i][ct][r]);
                }
            }
        }
    __syncthreads();
    const int bidx = m0 >> 11, mloc = m0 & 2047;
#pragma unroll
    for (int i = 0; i < 4; i++) {
        int cg = i * 256 + t;
        int h = cg >> 3, cc = cg & 7;
        ulonglong2 v = *(const ulonglong2*)&SM[h * 64 + ((cc ^ (h & 7)) << 3)];
        *(ulonglong2*)&Vt[((size_t)bidx * HH + h) * SS + mloc + cc * 8] = v;
    }
}

// ---------------------------------------------------------------------------
// Flash attention — R6 measured-best, UNCHANGED. (vector-load staging, padded
// LDS Ks 136 / Vs 72 / Ps 72, balanced contiguous chunks <=4 k-tiles,
// full-line permuted 16B Po stores.) grid (144, 8), block 256.
// ---------------------------------------------------------------------------
__global__ __launch_bounds__(256, 3)
void attn(const unsigned short* __restrict__ Q, const unsigned short* __restrict__ K,
          const unsigned short* __restrict__ Vt,
          unsigned short* __restrict__ Po, float* __restrict__ Pm, float* __restrict__ Pl)
{
    const int c = blockIdx.x, b = blockIdx.y;
    int g = (int)((__builtin_sqrtf(2.0f * c + 1.0f) - 1.0f) * 0.5f);
    while (2 * (g + 1) * (g + 2) <= c) g++;
    while (2 * g * (g + 1) > c) g--;
    const int idx = c - 2 * g * (g + 1);
    const int qt = 4 * g + idx / (g + 1);
    const int ch = idx % (g + 1);
    const int q0 = qt * 64;
    const int kt0 = ch * 4;
    const int kt1 = min(kt0 + 4, qt + 1);

    const int t = threadIdx.x, lane = t & 63;
    const int wave = t >> 6, quad = lane >> 4, l16 = lane & 15;

    __shared__ __align__(16) unsigned short Ks[64 * 136];
    __shared__ __align__(16) unsigned short Vs[128 * 72];
    __shared__ __align__(16) unsigned short Ps[4][16 * 72];

    bf16x8 qf[4];
    {
        const unsigned short* qrow = Q + (size_t)(b * SS + q0 + wave * 16 + l16) * HH;
#pragma unroll
        for (int dd = 0; dd < 4; dd++)
            qf[dd] = *(const bf16x8*)(qrow + dd * 32 + quad * 8);
    }

    f32x4 o[8];
#pragma unroll
    for (int j = 0; j < 8; j++) o[j] = (f32x4)0.0f;
    f32x4 o9 = (f32x4)0.0f;
    float mrow[4];
#pragma unroll
    for (int r = 0; r < 4; r++) mrow[r] = -1e30f;

    const float sscale = 0.08838834764831845f * 1.4426950408889634f;

    bf16x8 ones;
    {
        short e = (l16 == 0) ? (short)0x3F80 : (short)0;
        ones = (bf16x8){e, e, e, e, e, e, e, e};
    }

    for (int kt = kt0; kt < kt1; kt++) {
        const int k0 = kt * 64;
        __syncthreads();
#pragma unroll
        for (int it = 0; it < 4; it++) {
            int flat = it * 256 + t;
            int row = flat >> 4, c8 = (flat & 15) * 8;
            *(ulonglong2*)&Ks[row * 136 + c8] =
                *(const ulonglong2*)(K + (size_t)(b * SS + k0 + row) * HH + c8);
        }
#pragma unroll
        for (int it = 0; it < 4; it++) {
            int flat = it * 256 + t;
            int row = flat >> 3, c8 = (flat & 7) * 8;
            *(ulonglong2*)&Vs[row * 72 + c8] =
                *(const ulonglong2*)(Vt + ((size_t)b * HH + row) * SS + k0 + c8);
        }
        __syncthreads();

        f32x4 s[4];
#pragma unroll
        for (int ct = 0; ct < 4; ct++) s[ct] = (f32x4)0.0f;
#pragma unroll
        for (int dd = 0; dd < 4; dd++) {
#pragma unroll
            for (int ct = 0; ct < 4; ct++) {
                bf16x8 kfr = *(const bf16x8*)&Ks[(ct * 16 + l16) * 136 + dd * 32 + quad * 8];
                s[ct] = __builtin_amdgcn_mfma_f32_16x16x32_bf16(qf[dd], kfr, s[ct], 0, 0, 0);
            }
        }

        const bool diag = (kt == qt);
        float sv[4][4];
#pragma unroll
        for (int ct = 0; ct < 4; ct++) {
            int col = k0 + ct * 16 + l16;
#pragma unroll
            for (int r = 0; r < 4; r++) {
                float v = s[ct][r] * sscale;
                if (diag) {
                    int row = q0 + wave * 16 + quad * 4 + r;
                    if (col > row) v = -1e30f;
                }
                sv[ct][r] = v;
            }
        }

        float alpha[4];
#pragma unroll
        for (int r = 0; r < 4; r++) {
            float v = fmaxf(fmaxf(sv[0][r], sv[1][r]), fmaxf(sv[2][r], sv[3][r]));
            v = fmaxf(v, __shfl_xor(v, 1));
            v = fmaxf(v, __shfl_xor(v, 2));
            v = fmaxf(v, __shfl_xor(v, 4));
            v = fmaxf(v, __shfl_xor(v, 8));
            float mnew = fmaxf(mrow[r], v);
            alpha[r] = exp2f(mrow[r] - mnew);
            mrow[r]  = mnew;
        }
#pragma unroll
        for (int ct = 0; ct < 4; ct++) {
#pragma unroll
            for (int r = 0; r < 4; r++) {
                float p = exp2f(sv[ct][r] - mrow[r]);
                Ps[wave][(quad * 4 + r) * 72 + ct * 16 + l16] = f2bf(p);
            }
        }
#pragma unroll
        for (int j = 0; j < 8; j++)
#pragma unroll
            for (int r = 0; r < 4; r++) o[j][r] *= alpha[r];
#pragma unroll
        for (int r = 0; r < 4; r++) o9[r] *= alpha[r];

#pragma unroll
        for (int kk = 0; kk < 2; kk++) {
            bf16x8 pf = *(const bf16x8*)&Ps[wave][l16 * 72 + kk * 32 + quad * 8];
#pragma unroll
            for (int j = 0; j < 8; j++) {
                bf16x8 vf = *(const bf16x8*)&Vs[(j * 16 + l16) * 72 + kk * 32 + quad * 8];
                o[j] = __builtin_amdgcn_mfma_f32_16x16x32_bf16(pf, vf, o[j], 0, 0, 0);
            }
            o9 = __builtin_amdgcn_mfma_f32_16x16x32_bf16(pf, ones, o9, 0, 0, 0);
        }
    }

    const size_t pidx = (size_t)b * NCH + c;
    const size_t pobase = pidx * (64 * 128);
    const size_t mbase  = pidx * 64;
#pragma unroll
    for (int r = 0; r < 4; r++) {
        int row = wave * 16 + quad * 4 + r;
        if (l16 == 0) { Pm[mbase + row] = mrow[r]; Pl[mbase + row] = o9[r]; }
        ushort8 val;
#pragma unroll
        for (int j = 0; j < 8; j++) val[j] = f2bf(o[j][r]);
        *(ushort8*)&Po[pobase + (size_t)row * 128 + l16 * 8] = val;
    }
}

// ---------------------------------------------------------------------------
// Combine — UNCHANGED from R6. grid (32, 8, 4), 16 q-rows per block.
// ---------------------------------------------------------------------------
__global__ __launch_bounds__(256)
void combine(const unsigned short* __restrict__ Po, const float* __restrict__ Pm,
             const float* __restrict__ Pl, float* __restrict__ Out)
{
    const int qt = blockIdx.x, b = blockIdx.y, qr = blockIdx.z;
    const int g = qt >> 2;
    const int n_ch = g + 1;
    const int cbase = 2 * g * (g + 1) + (qt - 4 * g) * (g + 1);
    const size_t p0 = (size_t)b * NCH + cbase;
    const int t = threadIdx.x;
    const int p = t & 127;
    const int col = (p & 7) * 16 + (p >> 3);
    const int rh = t >> 7;

    __shared__ float sm[8][16], sl[8][16], sw[8][16];
    __shared__ float sinv[16];

    if (t < 128) {
        int s = t >> 4, row = t & 15;
        float mv = -1e30f, lv = 0.0f;
        if (s < n_ch) {
            mv = Pm[(p0 + s) * 64 + qr * 16 + row];
            lv = Pl[(p0 + s) * 64 + qr * 16 + row];
        }
        sm[s][row] = mv; sl[s][row] = lv;
    }
    __syncthreads();
    if (t < 16) {
        int row = t;
        float ms = sm[0][row];
#pragma unroll
        for (int s = 1; s < 8; s++) ms = fmaxf(ms, sm[s][row]);
        float l = 0.0f;
#pragma unroll
        for (int s = 0; s < 8; s++) {
            float w = (sm[s][row] > -1e29f) ? exp2f(sm[s][row] - ms) : 0.0f;
            sw[s][row] = w;
            l += w * sl[s][row];
        }
        sinv[row] = 1.0f / l;
    }
    __syncthreads();

#pragma unroll
    for (int pass = 0; pass < 8; pass++) {
        int row = pass * 2 + rh;
        int grow = qr * 16 + row;
        float acc = 0.0f;
#pragma unroll
        for (int s = 0; s < 8; s++) {
            int ss = (s < n_ch) ? s : 0;
            acc += sw[s][row] * bf2f(Po[(p0 + ss) * 8192 + (size_t)grow * 128 + p]);
        }
        Out[((size_t)b * SS + qt * 64 + grow) * HH + col] = acc * sinv[row];
    }
}

extern "C" void kernel_launch(void* const* d_in, const int* in_sizes, int n_in,
                              void* d_out, int out_size, void* d_ws, size_t ws_size,
                              hipStream_t stream) {
    const float* X    = (const float*)d_in[0];
    const float* mask = (const float*)d_in[1];
    const float* Wq   = (const float*)d_in[2];
    const float* Wk   = (const float*)d_in[3];
    const float* Wv   = (const float*)d_in[4];

    char* ws = (char*)d_ws;
    unsigned short* Wb = (unsigned short*)ws; ws += (size_t)384 * EE * 2;      // 0.59 MB
    unsigned short* Q  = (unsigned short*)ws; ws += (size_t)MM * HH * 2;       // 4 MB
    unsigned short* Kb = (unsigned short*)ws; ws += (size_t)MM * HH * 2;       // 4 MB
    unsigned short* Vt = (unsigned short*)ws; ws += (size_t)MM * HH * 2;       // 4 MB
    unsigned short* Po = (unsigned short*)ws; ws += (size_t)BB * NCH * 64 * 128 * 2; // 18.9 MB
    float* Pm = (float*)ws; ws += (size_t)BB * NCH * 64 * 4;
    float* Pl = (float*)ws;

    wcvt<<<288, 256, 0, stream>>>(Wq, Wk, Wv, Wb);
    qkv_fused<<<256, 256, 0, stream>>>(X, mask, Wb, Q, Kb, Vt);
    attn<<<dim3(NCH, BB), 256, 0, stream>>>(Q, Kb, Vt, Po, Pm, Pl);
    combine<<<dim3(NQT, BB, 4), 256, 0, stream>>>(Po, Pm, Pl, (float*)d_out);
}

// Round 8
// 157.033 us; speedup vs baseline: 1.0079x; 1.0079x over previous
//
#include <hip/hip_runtime.h>
#include <hip/hip_bf16.h>

// Problem constants: B=8, S=2048, E=768, HEAD=128
#define BB 8
#define SS 2048
#define EE 768
#define HH 128
#define MM (BB*SS)     // 16384
#define NQT 32         // 64-row q-tiles per batch
#define NCH 144        // chunks per batch: sum_{qt} ceil((qt+1)/4)

typedef __attribute__((ext_vector_type(8))) short bf16x8;
typedef __attribute__((ext_vector_type(8))) unsigned short ushort8;
typedef __attribute__((ext_vector_type(4))) float f32x4;

__device__ __forceinline__ unsigned short f2bf(float x) {
    unsigned int u = __float_as_uint(x);
    u += 0x7fff + ((u >> 16) & 1);   // RNE
    return (unsigned short)(u >> 16);
}
__device__ __forceinline__ float bf2f(unsigned short h) {
    return __uint_as_float(((unsigned int)h) << 16);
}
// async global->LDS, 16B per lane; LDS dest = wave-uniform base + lane*16
__device__ __forceinline__ void gld16(const unsigned short* g, unsigned short* l) {
    __builtin_amdgcn_global_load_lds(
        (const __attribute__((address_space(1))) unsigned int*)g,
        (__attribute__((address_space(3))) unsigned int*)l, 16, 0, 0);
}

// ---------------------------------------------------------------------------
// wcvt: Wb = bf16([Wq;Wk;Wv]) [384][768]. grid 288, ~2 us.
// ---------------------------------------------------------------------------
__global__ __launch_bounds__(256)
void wcvt(const float* __restrict__ Wq, const float* __restrict__ Wk,
          const float* __restrict__ Wv, unsigned short* __restrict__ Wb) {
    int i4 = (blockIdx.x * 256 + threadIdx.x) * 4;        // < 294912
    const float* src; int off;
    if (i4 < 98304)       { src = Wq; off = i4; }
    else if (i4 < 196608) { src = Wk; off = i4 - 98304; }
    else                  { src = Wv; off = i4 - 196608; }
    float4 v = *(const float4*)(src + off);
    ushort4 o;
    o.x = f2bf(v.x); o.y = f2bf(v.y); o.z = f2bf(v.z); o.w = f2bf(v.w);
    *(ushort4*)(Wb + i4) = o;
}

// ---------------------------------------------------------------------------
// Fused QKV GEMM v2: X read once per (m,nh) pair (pair shares X via L2/L3).
// grid (2 = n-half FASTEST, 256 = m-tile): block = 64 rows x 192 cols.
// BK=32, 24 k-iters, double-buffered LDS 2 x (A 4KB + B 12KB) = 32KB
// -> 2 blocks/CU (launch_bounds(256,2), acc 4x3 keeps VGPR <= 128).
// Pipeline per iter: barrier -> issue next B gld16 + next X float4 loads ->
// 12 MFMA/wave on current -> convert+ds_write next A.
// ---------------------------------------------------------------------------
__global__ __launch_bounds__(256, 2)
void qkv_fused(const float* __restrict__ X, const float* __restrict__ mask,
               const unsigned short* __restrict__ Wb,
               unsigned short* __restrict__ Q, unsigned short* __restrict__ K,
               unsigned short* __restrict__ Vt)
{
    const int nh = blockIdx.x;               // n-half: cols [nh*192, nh*192+192)
    const int m0 = blockIdx.y * 64;
    const int n0g = nh * 192;                // row offset into Wb [384][768]

    // per-buf: A 2048 shorts | B 6144 shorts; two bufs = 16384 shorts (32KB)
    __shared__ __align__(16) unsigned short SM[16384];

    const int t = threadIdx.x, lane = t & 63;
    const int quad = lane >> 4, l16 = lane & 15;
    const int wave = t >> 6;
    const int wub = (t & 192) * 8;           // wave-uniform base (shorts)

    // A-staging assignment: thread -> (row = t>>2, 8-col segment = t&3)
    const int arow = t >> 2, aseg = t & 3;
    const int ap = aseg ^ ((arow >> 1) & 3); // swizzled physical slot
    const float* xrow = X + (size_t)(m0 + arow) * EE;
    const float amk = mask[m0 + arow];

    f32x4 acc[4][3];
#pragma unroll
    for (int i = 0; i < 4; i++)
#pragma unroll
        for (int ct = 0; ct < 3; ct++) acc[i][ct] = (f32x4)0.0f;

    // ---- prologue: stage k-slice 0 into buf 0 ----
    {
        unsigned short* Bd = SM + 2048;
#pragma unroll
        for (int i = 0; i < 3; i++) {        // B: 192 rows x 4 chunks
            int cg = i * 256 + t;
            int row = cg >> 2;
            int cc = (cg & 3) ^ ((row >> 1) & 3);
            gld16(Wb + (size_t)(n0g + row) * EE + cc * 8, Bd + i * 2048 + wub);
        }
        float4 xa = *(const float4*)(xrow + aseg * 8);
        float4 xb = *(const float4*)(xrow + aseg * 8 + 4);
        ushort8 u;
        u[0] = f2bf(xa.x * amk); u[1] = f2bf(xa.y * amk);
        u[2] = f2bf(xa.z * amk); u[3] = f2bf(xa.w * amk);
        u[4] = f2bf(xb.x * amk); u[5] = f2bf(xb.y * amk);
        u[6] = f2bf(xb.z * amk); u[7] = f2bf(xb.w * amk);
        *(ushort8*)&SM[arow * 32 + ap * 8] = u;
    }

    for (int kt = 0; kt < 24; kt++) {
        const int cur = kt & 1, nxt = cur ^ 1;
        __syncthreads();   // staging of `cur` (gld16 vmcnt + ds_writes) complete

        float4 xa, xb;
        const bool more = (kt + 1 < 24);
        if (more) {
            const int kn = (kt + 1) * 32;
            unsigned short* Bd = SM + nxt * 8192 + 2048;
#pragma unroll
            for (int i = 0; i < 3; i++) {
                int cg = i * 256 + t;
                int row = cg >> 2;
                int cc = (cg & 3) ^ ((row >> 1) & 3);
                gld16(Wb + (size_t)(n0g + row) * EE + kn + cc * 8, Bd + i * 2048 + wub);
            }
            xa = *(const float4*)(xrow + kn + aseg * 8);
            xb = *(const float4*)(xrow + kn + aseg * 8 + 4);
        }

        // compute on current buffer
        {
            const unsigned short* Ab = SM + cur * 8192;
            const unsigned short* Bb = Ab + 2048;
            bf16x8 a[4], bfr[3];
#pragma unroll
            for (int i = 0; i < 4; i++) {
                int row = i * 16 + l16;
                a[i] = *(const bf16x8*)&Ab[row * 32 + ((quad ^ ((row >> 1) & 3)) << 3)];
            }
#pragma unroll
            for (int ct = 0; ct < 3; ct++) {
                int row = wave * 48 + ct * 16 + l16;
                bfr[ct] = *(const bf16x8*)&Bb[row * 32 + ((quad ^ ((row >> 1) & 3)) << 3)];
            }
#pragma unroll
            for (int i = 0; i < 4; i++)
#pragma unroll
                for (int ct = 0; ct < 3; ct++)
                    acc[i][ct] = __builtin_amdgcn_mfma_f32_16x16x32_bf16(a[i], bfr[ct], acc[i][ct], 0, 0, 0);
        }

        if (more) {   // convert + ds_write next A (X-load vmcnt wait lands here)
            ushort8 u;
            u[0] = f2bf(xa.x * amk); u[1] = f2bf(xa.y * amk);
            u[2] = f2bf(xa.z * amk); u[3] = f2bf(xa.w * amk);
            u[4] = f2bf(xb.x * amk); u[5] = f2bf(xb.y * amk);
            u[6] = f2bf(xb.z * amk); u[7] = f2bf(xb.w * amk);
            *(ushort8*)&SM[nxt * 8192 + arow * 32 + ap * 8] = u;
        }
    }

    // ---- epilogue: route n -> Q / K (direct); V via LDS-bounce transpose ----
    // C/D layout: row = quad*4 + r, col = l16  [measured: m89/m91]
#pragma unroll
    for (int i = 0; i < 4; i++)
#pragma unroll
        for (int r = 0; r < 4; r++) {
            int m = m0 + i * 16 + quad * 4 + r;
#pragma unroll
            for (int ct = 0; ct < 3; ct++) {
                int n = n0g + wave * 48 + ct * 16 + l16;
                if (n < 128)      Q[(size_t)m * HH + n] = f2bf(acc[i][ct][r]);
                else if (n < 256) K[(size_t)m * HH + (n - 128)] = f2bf(acc[i][ct][r]);
            }
        }
    if (nh == 1) {
        // V cols 256..383 live here. Bounce through SM[0..8192): [h][tok64].
        // Safe: compute(kt=23) read buf1 (SM+8192); buf0 is idle now.
#pragma unroll
        for (int i = 0; i < 4; i++)
#pragma unroll
            for (int r = 0; r < 4; r++) {
                int tok = i * 16 + quad * 4 + r;
                int ccw = tok >> 3, wd = tok & 7;
#pragma unroll
                for (int ct = 0; ct < 3; ct++) {
                    int n = n0g + wave * 48 + ct * 16 + l16;
                    if (n >= 256) {
                        int h = n - 256;
                        SM[h * 64 + ((ccw ^ (h & 7)) << 3) + wd] = f2bf(acc[i][ct][r]);
                    }
                }
            }
        __syncthreads();
        const int bidx = m0 >> 11, mloc = m0 & 2047;
#pragma unroll
        for (int i = 0; i < 4; i++) {
            int cg = i * 256 + t;
            int h = cg >> 3, cc = cg & 7;
            ulonglong2 v = *(const ulonglong2*)&SM[h * 64 + ((cc ^ (h & 7)) << 3)];
            *(ulonglong2*)&Vt[((size_t)bidx * HH + h) * SS + mloc + cc * 8] = v;
        }
    }
}

// ---------------------------------------------------------------------------
// Flash attention — R6 measured-best, UNCHANGED. (vector-load staging, padded
// LDS Ks 136 / Vs 72 / Ps 72, balanced contiguous chunks <=4 k-tiles,
// full-line permuted 16B Po stores.) grid (144, 8), block 256.
// ---------------------------------------------------------------------------
__global__ __launch_bounds__(256, 3)
void attn(const unsigned short* __restrict__ Q, const unsigned short* __restrict__ K,
          const unsigned short* __restrict__ Vt,
          unsigned short* __restrict__ Po, float* __restrict__ Pm, float* __restrict__ Pl)
{
    const int c = blockIdx.x, b = blockIdx.y;
    int g = (int)((__builtin_sqrtf(2.0f * c + 1.0f) - 1.0f) * 0.5f);
    while (2 * (g + 1) * (g + 2) <= c) g++;
    while (2 * g * (g + 1) > c) g--;
    const int idx = c - 2 * g * (g + 1);
    const int qt = 4 * g + idx / (g + 1);
    const int ch = idx % (g + 1);
    const int q0 = qt * 64;
    const int kt0 = ch * 4;
    const int kt1 = min(kt0 + 4, qt + 1);

    const int t = threadIdx.x, lane = t & 63;
    const int wave = t >> 6, quad = lane >> 4, l16 = lane & 15;

    __shared__ __align__(16) unsigned short Ks[64 * 136];
    __shared__ __align__(16) unsigned short Vs[128 * 72];
    __shared__ __align__(16) unsigned short Ps[4][16 * 72];

    bf16x8 qf[4];
    {
        const unsigned short* qrow = Q + (size_t)(b * SS + q0 + wave * 16 + l16) * HH;
#pragma unroll
        for (int dd = 0; dd < 4; dd++)
            qf[dd] = *(const bf16x8*)(qrow + dd * 32 + quad * 8);
    }

    f32x4 o[8];
#pragma unroll
    for (int j = 0; j < 8; j++) o[j] = (f32x4)0.0f;
    f32x4 o9 = (f32x4)0.0f;
    float mrow[4];
#pragma unroll
    for (int r = 0; r < 4; r++) mrow[r] = -1e30f;

    const float sscale = 0.08838834764831845f * 1.4426950408889634f;

    bf16x8 ones;
    {
        short e = (l16 == 0) ? (short)0x3F80 : (short)0;
        ones = (bf16x8){e, e, e, e, e, e, e, e};
    }

    for (int kt = kt0; kt < kt1; kt++) {
        const int k0 = kt * 64;
        __syncthreads();
#pragma unroll
        for (int it = 0; it < 4; it++) {
            int flat = it * 256 + t;
            int row = flat >> 4, c8 = (flat & 15) * 8;
            *(ulonglong2*)&Ks[row * 136 + c8] =
                *(const ulonglong2*)(K + (size_t)(b * SS + k0 + row) * HH + c8);
        }
#pragma unroll
        for (int it = 0; it < 4; it++) {
            int flat = it * 256 + t;
            int row = flat >> 3, c8 = (flat & 7) * 8;
            *(ulonglong2*)&Vs[row * 72 + c8] =
                *(const ulonglong2*)(Vt + ((size_t)b * HH + row) * SS + k0 + c8);
        }
        __syncthreads();

        f32x4 s[4];
#pragma unroll
        for (int ct = 0; ct < 4; ct++) s[ct] = (f32x4)0.0f;
#pragma unroll
        for (int dd = 0; dd < 4; dd++) {
#pragma unroll
            for (int ct = 0; ct < 4; ct++) {
                bf16x8 kfr = *(const bf16x8*)&Ks[(ct * 16 + l16) * 136 + dd * 32 + quad * 8];
                s[ct] = __builtin_amdgcn_mfma_f32_16x16x32_bf16(qf[dd], kfr, s[ct], 0, 0, 0);
            }
        }

        const bool diag = (kt == qt);
        float sv[4][4];
#pragma unroll
        for (int ct = 0; ct < 4; ct++) {
            int col = k0 + ct * 16 + l16;
#pragma unroll
            for (int r = 0; r < 4; r++) {
                float v = s[ct][r] * sscale;
                if (diag) {
                    int row = q0 + wave * 16 + quad * 4 + r;
                    if (col > row) v = -1e30f;
                }
                sv[ct][r] = v;
            }
        }

        float alpha[4];
#pragma unroll
        for (int r = 0; r < 4; r++) {
            float v = fmaxf(fmaxf(sv[0][r], sv[1][r]), fmaxf(sv[2][r], sv[3][r]));
            v = fmaxf(v, __shfl_xor(v, 1));
            v = fmaxf(v, __shfl_xor(v, 2));
            v = fmaxf(v, __shfl_xor(v, 4));
            v = fmaxf(v, __shfl_xor(v, 8));
            float mnew = fmaxf(mrow[r], v);
            alpha[r] = exp2f(mrow[r] - mnew);
            mrow[r]  = mnew;
        }
#pragma unroll
        for (int ct = 0; ct < 4; ct++) {
#pragma unroll
            for (int r = 0; r < 4; r++) {
                float p = exp2f(sv[ct][r] - mrow[r]);
                Ps[wave][(quad * 4 + r) * 72 + ct * 16 + l16] = f2bf(p);
            }
        }
#pragma unroll
        for (int j = 0; j < 8; j++)
#pragma unroll
            for (int r = 0; r < 4; r++) o[j][r] *= alpha[r];
#pragma unroll
        for (int r = 0; r < 4; r++) o9[r] *= alpha[r];

#pragma unroll
        for (int kk = 0; kk < 2; kk++) {
            bf16x8 pf = *(const bf16x8*)&Ps[wave][l16 * 72 + kk * 32 + quad * 8];
#pragma unroll
            for (int j = 0; j < 8; j++) {
                bf16x8 vf = *(const bf16x8*)&Vs[(j * 16 + l16) * 72 + kk * 32 + quad * 8];
                o[j] = __builtin_amdgcn_mfma_f32_16x16x32_bf16(pf, vf, o[j], 0, 0, 0);
            }
            o9 = __builtin_amdgcn_mfma_f32_16x16x32_bf16(pf, ones, o9, 0, 0, 0);
        }
    }

    const size_t pidx = (size_t)b * NCH + c;
    const size_t pobase = pidx * (64 * 128);
    const size_t mbase  = pidx * 64;
#pragma unroll
    for (int r = 0; r < 4; r++) {
        int row = wave * 16 + quad * 4 + r;
        if (l16 == 0) { Pm[mbase + row] = mrow[r]; Pl[mbase + row] = o9[r]; }
        ushort8 val;
#pragma unroll
        for (int j = 0; j < 8; j++) val[j] = f2bf(o[j][r]);
        *(ushort8*)&Po[pobase + (size_t)row * 128 + l16 * 8] = val;
    }
}

// ---------------------------------------------------------------------------
// Combine — UNCHANGED from R6. grid (32, 8, 4), 16 q-rows per block.
// ---------------------------------------------------------------------------
__global__ __launch_bounds__(256)
void combine(const unsigned short* __restrict__ Po, const float* __restrict__ Pm,
             const float* __restrict__ Pl, float* __restrict__ Out)
{
    const int qt = blockIdx.x, b = blockIdx.y, qr = blockIdx.z;
    const int g = qt >> 2;
    const int n_ch = g + 1;
    const int cbase = 2 * g * (g + 1) + (qt - 4 * g) * (g + 1);
    const size_t p0 = (size_t)b * NCH + cbase;
    const int t = threadIdx.x;
    const int p = t & 127;
    const int col = (p & 7) * 16 + (p >> 3);
    const int rh = t >> 7;

    __shared__ float sm[8][16], sl[8][16], sw[8][16];
    __shared__ float sinv[16];

    if (t < 128) {
        int s = t >> 4, row = t & 15;
        float mv = -1e30f, lv = 0.0f;
        if (s < n_ch) {
            mv = Pm[(p0 + s) * 64 + qr * 16 + row];
            lv = Pl[(p0 + s) * 64 + qr * 16 + row];
        }
        sm[s][row] = mv; sl[s][row] = lv;
    }
    __syncthreads();
    if (t < 16) {
        int row = t;
        float ms = sm[0][row];
#pragma unroll
        for (int s = 1; s < 8; s++) ms = fmaxf(ms, sm[s][row]);
        float l = 0.0f;
#pragma unroll
        for (int s = 0; s < 8; s++) {
            float w = (sm[s][row] > -1e29f) ? exp2f(sm[s][row] - ms) : 0.0f;
            sw[s][row] = w;
            l += w * sl[s][row];
        }
        sinv[row] = 1.0f / l;
    }
    __syncthreads();

#pragma unroll
    for (int pass = 0; pass < 8; pass++) {
        int row = pass * 2 + rh;
        int grow = qr * 16 + row;
        float acc = 0.0f;
#pragma unroll
        for (int s = 0; s < 8; s++) {
            int ss = (s < n_ch) ? s : 0;
            acc += sw[s][row] * bf2f(Po[(p0 + ss) * 8192 + (size_t)grow * 128 + p]);
        }
        Out[((size_t)b * SS + qt * 64 + grow) * HH + col] = acc * sinv[row];
    }
}

extern "C" void kernel_launch(void* const* d_in, const int* in_sizes, int n_in,
                              void* d_out, int out_size, void* d_ws, size_t ws_size,
                              hipStream_t stream) {
    const float* X    = (const float*)d_in[0];
    const float* mask = (const float*)d_in[1];
    const float* Wq   = (const float*)d_in[2];
    const float* Wk   = (const float*)d_in[3];
    const float* Wv   = (const float*)d_in[4];

    char* ws = (char*)d_ws;
    unsigned short* Wb = (unsigned short*)ws; ws += (size_t)384 * EE * 2;      // 0.59 MB
    unsigned short* Q  = (unsigned short*)ws; ws += (size_t)MM * HH * 2;       // 4 MB
    unsigned short* Kb = (unsigned short*)ws; ws += (size_t)MM * HH * 2;       // 4 MB
    unsigned short* Vt = (unsigned short*)ws; ws += (size_t)MM * HH * 2;       // 4 MB
    unsigned short* Po = (unsigned short*)ws; ws += (size_t)BB * NCH * 64 * 128 * 2; // 18.9 MB
    float* Pm = (float*)ws; ws += (size_t)BB * NCH * 64 * 4;
    float* Pl = (float*)ws;

    wcvt<<<288, 256, 0, stream>>>(Wq, Wk, Wv, Wb);
    qkv_fused<<<dim3(2, 256), 256, 0, stream>>>(X, mask, Wb, Q, Kb, Vt);
    attn<<<dim3(NCH, BB), 256, 0, stream>>>(Q, Kb, Vt, Po, Pm, Pl);
    combine<<<dim3(NQT, BB, 4), 256, 0, stream>>>(Po, Pm, Pl, (float*)d_out);
}

// Round 9
// 154.982 us; speedup vs baseline: 1.0213x; 1.0132x over previous
//
#include <hip/hip_runtime.h>
#include <hip/hip_bf16.h>

// Problem constants: B=8, S=2048, E=768, HEAD=128
#define BB 8
#define SS 2048
#define EE 768
#define HH 128
#define MM (BB*SS)     // 16384
#define NQT 32         // 64-row q-tiles per batch
#define NCH 144        // chunks per batch: sum_{qt} ceil((qt+1)/4)

typedef __attribute__((ext_vector_type(8))) short bf16x8;
typedef __attribute__((ext_vector_type(8))) unsigned short ushort8;
typedef __attribute__((ext_vector_type(4))) float f32x4;

__device__ __forceinline__ unsigned short f2bf(float x) {
    unsigned int u = __float_as_uint(x);
    u += 0x7fff + ((u >> 16) & 1);   // RNE
    return (unsigned short)(u >> 16);
}
__device__ __forceinline__ float bf2f(unsigned short h) {
    return __uint_as_float(((unsigned int)h) << 16);
}
// async global->LDS, 16B per lane; LDS dest = wave-uniform base + lane*16
__device__ __forceinline__ void gld16(const unsigned short* g, unsigned short* l) {
    __builtin_amdgcn_global_load_lds(
        (const __attribute__((address_space(1))) unsigned int*)g,
        (__attribute__((address_space(3))) unsigned int*)l, 16, 0, 0);
}

// ---------------------------------------------------------------------------
// wcvt: Wb = bf16([Wq;Wk;Wv]) [384][768]. grid 288, ~2 us.
// ---------------------------------------------------------------------------
__global__ __launch_bounds__(256)
void wcvt(const float* __restrict__ Wq, const float* __restrict__ Wk,
          const float* __restrict__ Wv, unsigned short* __restrict__ Wb) {
    int i4 = (blockIdx.x * 256 + threadIdx.x) * 4;        // < 294912
    const float* src; int off;
    if (i4 < 98304)       { src = Wq; off = i4; }
    else if (i4 < 196608) { src = Wk; off = i4 - 98304; }
    else                  { src = Wv; off = i4 - 196608; }
    float4 v = *(const float4*)(src + off);
    ushort4 o;
    o.x = f2bf(v.x); o.y = f2bf(v.y); o.z = f2bf(v.z); o.w = f2bf(v.w);
    *(ushort4*)(Wb + i4) = o;
}

// ---------------------------------------------------------------------------
// Fused QKV GEMM v3: identical to v2 EXCEPT each block starts its k-loop at
// kstart = (blockIdx.y + nh*12) % 24 and wraps. Co-resident blocks stage
// DIFFERENT Wb k-slices at any instant -> no same-line L2 serialization on
// the shared weight matrix (the R7/R8 invariant: per-iter wall time tracked
// total identical-address gld16 bytes, not residency or per-block work).
// grid (2 = n-half, 256 = m-tile), BK=32, dbuf 32KB, 2 blocks/CU.
// ---------------------------------------------------------------------------
__global__ __launch_bounds__(256, 2)
void qkv_fused(const float* __restrict__ X, const float* __restrict__ mask,
               const unsigned short* __restrict__ Wb,
               unsigned short* __restrict__ Q, unsigned short* __restrict__ K,
               unsigned short* __restrict__ Vt)
{
    const int nh = blockIdx.x;               // n-half: cols [nh*192, nh*192+192)
    const int m0 = blockIdx.y * 64;
    const int n0g = nh * 192;                // row offset into Wb [384][768]
    int kstart = blockIdx.y + nh * 12;
    kstart -= (kstart / 24) * 24;            // % 24

    // per-buf: A 2048 shorts | B 6144 shorts; two bufs = 16384 shorts (32KB)
    __shared__ __align__(16) unsigned short SM[16384];

    const int t = threadIdx.x, lane = t & 63;
    const int quad = lane >> 4, l16 = lane & 15;
    const int wave = t >> 6;
    const int wub = (t & 192) * 8;           // wave-uniform base (shorts)

    // A-staging assignment: thread -> (row = t>>2, 8-col segment = t&3)
    const int arow = t >> 2, aseg = t & 3;
    const int ap = aseg ^ ((arow >> 1) & 3); // swizzled physical slot
    const float* xrow = X + (size_t)(m0 + arow) * EE;
    const float amk = mask[m0 + arow];

    f32x4 acc[4][3];
#pragma unroll
    for (int i = 0; i < 4; i++)
#pragma unroll
        for (int ct = 0; ct < 3; ct++) acc[i][ct] = (f32x4)0.0f;

    // ---- prologue: stage k-slice kstart into buf 0 ----
    {
        const int kc = kstart * 32;
        unsigned short* Bd = SM + 2048;
#pragma unroll
        for (int i = 0; i < 3; i++) {        // B: 192 rows x 4 chunks
            int cg = i * 256 + t;
            int row = cg >> 2;
            int cc = (cg & 3) ^ ((row >> 1) & 3);
            gld16(Wb + (size_t)(n0g + row) * EE + kc + cc * 8, Bd + i * 2048 + wub);
        }
        float4 xa = *(const float4*)(xrow + kc + aseg * 8);
        float4 xb = *(const float4*)(xrow + kc + aseg * 8 + 4);
        ushort8 u;
        u[0] = f2bf(xa.x * amk); u[1] = f2bf(xa.y * amk);
        u[2] = f2bf(xa.z * amk); u[3] = f2bf(xa.w * amk);
        u[4] = f2bf(xb.x * amk); u[5] = f2bf(xb.y * amk);
        u[6] = f2bf(xb.z * amk); u[7] = f2bf(xb.w * amk);
        *(ushort8*)&SM[arow * 32 + ap * 8] = u;
    }

    for (int v = 0; v < 24; v++) {
        const int cur = v & 1, nxt = cur ^ 1;
        __syncthreads();   // staging of `cur` (gld16 vmcnt + ds_writes) complete

        float4 xa, xb;
        const bool more = (v + 1 < 24);
        if (more) {
            int kn = kstart + v + 1;
            if (kn >= 24) kn -= 24;
            const int knc = kn * 32;
            unsigned short* Bd = SM + nxt * 8192 + 2048;
#pragma unroll
            for (int i = 0; i < 3; i++) {
                int cg = i * 256 + t;
                int row = cg >> 2;
                int cc = (cg & 3) ^ ((row >> 1) & 3);
                gld16(Wb + (size_t)(n0g + row) * EE + knc + cc * 8, Bd + i * 2048 + wub);
            }
            xa = *(const float4*)(xrow + knc + aseg * 8);
            xb = *(const float4*)(xrow + knc + aseg * 8 + 4);
        }

        // compute on current buffer
        {
            const unsigned short* Ab = SM + cur * 8192;
            const unsigned short* Bb = Ab + 2048;
            bf16x8 a[4], bfr[3];
#pragma unroll
            for (int i = 0; i < 4; i++) {
                int row = i * 16 + l16;
                a[i] = *(const bf16x8*)&Ab[row * 32 + ((quad ^ ((row >> 1) & 3)) << 3)];
            }
#pragma unroll
            for (int ct = 0; ct < 3; ct++) {
                int row = wave * 48 + ct * 16 + l16;
                bfr[ct] = *(const bf16x8*)&Bb[row * 32 + ((quad ^ ((row >> 1) & 3)) << 3)];
            }
#pragma unroll
            for (int i = 0; i < 4; i++)
#pragma unroll
                for (int ct = 0; ct < 3; ct++)
                    acc[i][ct] = __builtin_amdgcn_mfma_f32_16x16x32_bf16(a[i], bfr[ct], acc[i][ct], 0, 0, 0);
        }

        if (more) {   // convert + ds_write next A (X-load vmcnt wait lands here)
            ushort8 u;
            u[0] = f2bf(xa.x * amk); u[1] = f2bf(xa.y * amk);
            u[2] = f2bf(xa.z * amk); u[3] = f2bf(xa.w * amk);
            u[4] = f2bf(xb.x * amk); u[5] = f2bf(xb.y * amk);
            u[6] = f2bf(xb.z * amk); u[7] = f2bf(xb.w * amk);
            *(ushort8*)&SM[nxt * 8192 + arow * 32 + ap * 8] = u;
        }
    }

    // ---- epilogue: route n -> Q / K (direct); V via LDS-bounce transpose ----
    // C/D layout: row = quad*4 + r, col = l16  [measured: m89/m91]
#pragma unroll
    for (int i = 0; i < 4; i++)
#pragma unroll
        for (int r = 0; r < 4; r++) {
            int m = m0 + i * 16 + quad * 4 + r;
#pragma unroll
            for (int ct = 0; ct < 3; ct++) {
                int n = n0g + wave * 48 + ct * 16 + l16;
                if (n < 128)      Q[(size_t)m * HH + n] = f2bf(acc[i][ct][r]);
                else if (n < 256) K[(size_t)m * HH + (n - 128)] = f2bf(acc[i][ct][r]);
            }
        }
    if (nh == 1) {
        // V cols 256..383 live here. Bounce through SM[0..8192): [h][tok64].
        // Safe: compute(v=23) read one buf; both idle after final barrier-less
        // epilogue sync below.
        __syncthreads();
#pragma unroll
        for (int i = 0; i < 4; i++)
#pragma unroll
            for (int r = 0; r < 4; r++) {
                int tok = i * 16 + quad * 4 + r;
                int ccw = tok >> 3, wd = tok & 7;
#pragma unroll
                for (int ct = 0; ct < 3; ct++) {
                    int n = n0g + wave * 48 + ct * 16 + l16;
                    if (n >= 256) {
                        int h = n - 256;
                        SM[h * 64 + ((ccw ^ (h & 7)) << 3) + wd] = f2bf(acc[i][ct][r]);
                    }
                }
            }
        __syncthreads();
        const int bidx = m0 >> 11, mloc = m0 & 2047;
#pragma unroll
        for (int i = 0; i < 4; i++) {
            int cg = i * 256 + t;
            int h = cg >> 3, cc = cg & 7;
            ulonglong2 v2 = *(const ulonglong2*)&SM[h * 64 + ((cc ^ (h & 7)) << 3)];
            *(ulonglong2*)&Vt[((size_t)bidx * HH + h) * SS + mloc + cc * 8] = v2;
        }
    }
}

// ---------------------------------------------------------------------------
// Flash attention — R6 measured-best, UNCHANGED. grid (144, 8), block 256.
// ---------------------------------------------------------------------------
__global__ __launch_bounds__(256, 3)
void attn(const unsigned short* __restrict__ Q, const unsigned short* __restrict__ K,
          const unsigned short* __restrict__ Vt,
          unsigned short* __restrict__ Po, float* __restrict__ Pm, float* __restrict__ Pl)
{
    const int c = blockIdx.x, b = blockIdx.y;
    int g = (int)((__builtin_sqrtf(2.0f * c + 1.0f) - 1.0f) * 0.5f);
    while (2 * (g + 1) * (g + 2) <= c) g++;
    while (2 * g * (g + 1) > c) g--;
    const int idx = c - 2 * g * (g + 1);
    const int qt = 4 * g + idx / (g + 1);
    const int ch = idx % (g + 1);
    const int q0 = qt * 64;
    const int kt0 = ch * 4;
    const int kt1 = min(kt0 + 4, qt + 1);

    const int t = threadIdx.x, lane = t & 63;
    const int wave = t >> 6, quad = lane >> 4, l16 = lane & 15;

    __shared__ __align__(16) unsigned short Ks[64 * 136];
    __shared__ __align__(16) unsigned short Vs[128 * 72];
    __shared__ __align__(16) unsigned short Ps[4][16 * 72];

    bf16x8 qf[4];
    {
        const unsigned short* qrow = Q + (size_t)(b * SS + q0 + wave * 16 + l16) * HH;
#pragma unroll
        for (int dd = 0; dd < 4; dd++)
            qf[dd] = *(const bf16x8*)(qrow + dd * 32 + quad * 8);
    }

    f32x4 o[8];
#pragma unroll
    for (int j = 0; j < 8; j++) o[j] = (f32x4)0.0f;
    f32x4 o9 = (f32x4)0.0f;
    float mrow[4];
#pragma unroll
    for (int r = 0; r < 4; r++) mrow[r] = -1e30f;

    const float sscale = 0.08838834764831845f * 1.4426950408889634f;

    bf16x8 ones;
    {
        short e = (l16 == 0) ? (short)0x3F80 : (short)0;
        ones = (bf16x8){e, e, e, e, e, e, e, e};
    }

    for (int kt = kt0; kt < kt1; kt++) {
        const int k0 = kt * 64;
        __syncthreads();
#pragma unroll
        for (int it = 0; it < 4; it++) {
            int flat = it * 256 + t;
            int row = flat >> 4, c8 = (flat & 15) * 8;
            *(ulonglong2*)&Ks[row * 136 + c8] =
                *(const ulonglong2*)(K + (size_t)(b * SS + k0 + row) * HH + c8);
        }
#pragma unroll
        for (int it = 0; it < 4; it++) {
            int flat = it * 256 + t;
            int row = flat >> 3, c8 = (flat & 7) * 8;
            *(ulonglong2*)&Vs[row * 72 + c8] =
                *(const ulonglong2*)(Vt + ((size_t)b * HH + row) * SS + k0 + c8);
        }
        __syncthreads();

        f32x4 s[4];
#pragma unroll
        for (int ct = 0; ct < 4; ct++) s[ct] = (f32x4)0.0f;
#pragma unroll
        for (int dd = 0; dd < 4; dd++) {
#pragma unroll
            for (int ct = 0; ct < 4; ct++) {
                bf16x8 kfr = *(const bf16x8*)&Ks[(ct * 16 + l16) * 136 + dd * 32 + quad * 8];
                s[ct] = __builtin_amdgcn_mfma_f32_16x16x32_bf16(qf[dd], kfr, s[ct], 0, 0, 0);
            }
        }

        const bool diag = (kt == qt);
        float sv[4][4];
#pragma unroll
        for (int ct = 0; ct < 4; ct++) {
            int col = k0 + ct * 16 + l16;
#pragma unroll
            for (int r = 0; r < 4; r++) {
                float v = s[ct][r] * sscale;
                if (diag) {
                    int row = q0 + wave * 16 + quad * 4 + r;
                    if (col > row) v = -1e30f;
                }
                sv[ct][r] = v;
            }
        }

        float alpha[4];
#pragma unroll
        for (int r = 0; r < 4; r++) {
            float v = fmaxf(fmaxf(sv[0][r], sv[1][r]), fmaxf(sv[2][r], sv[3][r]));
            v = fmaxf(v, __shfl_xor(v, 1));
            v = fmaxf(v, __shfl_xor(v, 2));
            v = fmaxf(v, __shfl_xor(v, 4));
            v = fmaxf(v, __shfl_xor(v, 8));
            float mnew = fmaxf(mrow[r], v);
            alpha[r] = exp2f(mrow[r] - mnew);
            mrow[r]  = mnew;
        }
#pragma unroll
        for (int ct = 0; ct < 4; ct++) {
#pragma unroll
            for (int r = 0; r < 4; r++) {
                float p = exp2f(sv[ct][r] - mrow[r]);
                Ps[wave][(quad * 4 + r) * 72 + ct * 16 + l16] = f2bf(p);
            }
        }
#pragma unroll
        for (int j = 0; j < 8; j++)
#pragma unroll
            for (int r = 0; r < 4; r++) o[j][r] *= alpha[r];
#pragma unroll
        for (int r = 0; r < 4; r++) o9[r] *= alpha[r];

#pragma unroll
        for (int kk = 0; kk < 2; kk++) {
            bf16x8 pf = *(const bf16x8*)&Ps[wave][l16 * 72 + kk * 32 + quad * 8];
#pragma unroll
            for (int j = 0; j < 8; j++) {
                bf16x8 vf = *(const bf16x8*)&Vs[(j * 16 + l16) * 72 + kk * 32 + quad * 8];
                o[j] = __builtin_amdgcn_mfma_f32_16x16x32_bf16(pf, vf, o[j], 0, 0, 0);
            }
            o9 = __builtin_amdgcn_mfma_f32_16x16x32_bf16(pf, ones, o9, 0, 0, 0);
        }
    }

    const size_t pidx = (size_t)b * NCH + c;
    const size_t pobase = pidx * (64 * 128);
    const size_t mbase  = pidx * 64;
#pragma unroll
    for (int r = 0; r < 4; r++) {
        int row = wave * 16 + quad * 4 + r;
        if (l16 == 0) { Pm[mbase + row] = mrow[r]; Pl[mbase + row] = o9[r]; }
        ushort8 val;
#pragma unroll
        for (int j = 0; j < 8; j++) val[j] = f2bf(o[j][r]);
        *(ushort8*)&Po[pobase + (size_t)row * 128 + l16 * 8] = val;
    }
}

// ---------------------------------------------------------------------------
// Combine — UNCHANGED from R6. grid (32, 8, 4), 16 q-rows per block.
// ---------------------------------------------------------------------------
__global__ __launch_bounds__(256)
void combine(const unsigned short* __restrict__ Po, const float* __restrict__ Pm,
             const float* __restrict__ Pl, float* __restrict__ Out)
{
    const int qt = blockIdx.x, b = blockIdx.y, qr = blockIdx.z;
    const int g = qt >> 2;
    const int n_ch = g + 1;
    const int cbase = 2 * g * (g + 1) + (qt - 4 * g) * (g + 1);
    const size_t p0 = (size_t)b * NCH + cbase;
    const int t = threadIdx.x;
    const int p = t & 127;
    const int col = (p & 7) * 16 + (p >> 3);
    const int rh = t >> 7;

    __shared__ float sm[8][16], sl[8][16], sw[8][16];
    __shared__ float sinv[16];

    if (t < 128) {
        int s = t >> 4, row = t & 15;
        float mv = -1e30f, lv = 0.0f;
        if (s < n_ch) {
            mv = Pm[(p0 + s) * 64 + qr * 16 + row];
            lv = Pl[(p0 + s) * 64 + qr * 16 + row];
        }
        sm[s][row] = mv; sl[s][row] = lv;
    }
    __syncthreads();
    if (t < 16) {
        int row = t;
        float ms = sm[0][row];
#pragma unroll
        for (int s = 1; s < 8; s++) ms = fmaxf(ms, sm[s][row]);
        float l = 0.0f;
#pragma unroll
        for (int s = 0; s < 8; s++) {
            float w = (sm[s][row] > -1e29f) ? exp2f(sm[s][row] - ms) : 0.0f;
            sw[s][row] = w;
            l += w * sl[s][row];
        }
        sinv[row] = 1.0f / l;
    }
    __syncthreads();

#pragma unroll
    for (int pass = 0; pass < 8; pass++) {
        int row = pass * 2 + rh;
        int grow = qr * 16 + row;
        float acc = 0.0f;
#pragma unroll
        for (int s = 0; s < 8; s++) {
            int ss = (s < n_ch) ? s : 0;
            acc += sw[s][row] * bf2f(Po[(p0 + ss) * 8192 + (size_t)grow * 128 + p]);
        }
        Out[((size_t)b * SS + qt * 64 + grow) * HH + col] = acc * sinv[row];
    }
}

extern "C" void kernel_launch(void* const* d_in, const int* in_sizes, int n_in,
                              void* d_out, int out_size, void* d_ws, size_t ws_size,
                              hipStream_t stream) {
    const float* X    = (const float*)d_in[0];
    const float* mask = (const float*)d_in[1];
    const float* Wq   = (const float*)d_in[2];
    const float* Wk   = (const float*)d_in[3];
    const float* Wv   = (const float*)d_in[4];

    char* ws = (char*)d_ws;
    unsigned short* Wb = (unsigned short*)ws; ws += (size_t)384 * EE * 2;      // 0.59 MB
    unsigned short* Q  = (unsigned short*)ws; ws += (size_t)MM * HH * 2;       // 4 MB
    unsigned short* Kb = (unsigned short*)ws; ws += (size_t)MM * HH * 2;       // 4 MB
    unsigned short* Vt = (unsigned short*)ws; ws += (size_t)MM * HH * 2;       // 4 MB
    unsigned short* Po = (unsigned short*)ws; ws += (size_t)BB * NCH * 64 * 128 * 2; // 18.9 MB
    float* Pm = (float*)ws; ws += (size_t)BB * NCH * 64 * 4;
    float* Pl = (float*)ws;

    wcvt<<<288, 256, 0, stream>>>(Wq, Wk, Wv, Wb);
    qkv_fused<<<dim3(2, 256), 256, 0, stream>>>(X, mask, Wb, Q, Kb, Vt);
    attn<<<dim3(NCH, BB), 256, 0, stream>>>(Q, Kb, Vt, Po, Pm, Pl);
    combine<<<dim3(NQT, BB, 4), 256, 0, stream>>>(Po, Pm, Pl, (float*)d_out);
}